// Round 3
// baseline (1279.446 us; speedup 1.0000x reference)
//
#include <hip/hip_runtime.h>
#include <math.h>

// Problem constants: B=64, N=14*14*32=6272, DIN=8, D=16, M=10, C=10
#define NPOS 6272
#define DIN_ 8
#define DVEC 16
#define CCAP 10
#define JC 4                    // capsule positions per block
#define NBLK (NPOS / JC)        // 1568 blocks
#define PSTRIDE 1200            // padded partial row (floats)
#define ACC_FLOATS 1194         // S[160] + T[10] + ubar[64*16]
#define P_OFF 1280              // float offset of partials in ws

__device__ __forceinline__ uint32_t lds_off(const void* p) {
    return (uint32_t)(uintptr_t)p;   // low 32 bits of generic LDS ptr = LDS byte offset
}

// 16 u-components scaled by th, plus th itself, into S row at byte-offset ba.
// Native ds_add_f32: fire-and-forget, no CAS loop, no lgkmcnt wait.
__device__ __forceinline__ void lds_scatter17(uint32_t ba, const float* u, float th) {
    float t0 = th * u[0],  t1 = th * u[1],  t2 = th * u[2],  t3 = th * u[3];
    float t4 = th * u[4],  t5 = th * u[5],  t6 = th * u[6],  t7 = th * u[7];
    float t8 = th * u[8],  t9 = th * u[9],  t10 = th * u[10], t11 = th * u[11];
    float t12 = th * u[12], t13 = th * u[13], t14 = th * u[14], t15 = th * u[15];
    asm volatile(
        "ds_add_f32 %0, %1\n\t"
        "ds_add_f32 %0, %2 offset:4\n\t"
        "ds_add_f32 %0, %3 offset:8\n\t"
        "ds_add_f32 %0, %4 offset:12\n\t"
        "ds_add_f32 %0, %5 offset:16\n\t"
        "ds_add_f32 %0, %6 offset:20\n\t"
        "ds_add_f32 %0, %7 offset:24\n\t"
        "ds_add_f32 %0, %8 offset:28\n\t"
        "ds_add_f32 %0, %9 offset:32\n\t"
        "ds_add_f32 %0, %10 offset:36\n\t"
        "ds_add_f32 %0, %11 offset:40\n\t"
        "ds_add_f32 %0, %12 offset:44\n\t"
        "ds_add_f32 %0, %13 offset:48\n\t"
        "ds_add_f32 %0, %14 offset:52\n\t"
        "ds_add_f32 %0, %15 offset:56\n\t"
        "ds_add_f32 %0, %16 offset:60\n\t"
        "ds_add_f32 %0, %17 offset:64"
        :
        : "v"(ba), "v"(t0), "v"(t1), "v"(t2), "v"(t3), "v"(t4), "v"(t5), "v"(t6),
          "v"(t7), "v"(t8), "v"(t9), "v"(t10), "v"(t11), "v"(t12), "v"(t13),
          "v"(t14), "v"(t15), "v"(th)
        : "memory");
}

__device__ __forceinline__ void lds_scatter16(uint32_t ba, const float* u) {
    asm volatile(
        "ds_add_f32 %0, %1\n\t"
        "ds_add_f32 %0, %2 offset:4\n\t"
        "ds_add_f32 %0, %3 offset:8\n\t"
        "ds_add_f32 %0, %4 offset:12\n\t"
        "ds_add_f32 %0, %5 offset:16\n\t"
        "ds_add_f32 %0, %6 offset:20\n\t"
        "ds_add_f32 %0, %7 offset:24\n\t"
        "ds_add_f32 %0, %8 offset:28\n\t"
        "ds_add_f32 %0, %9 offset:32\n\t"
        "ds_add_f32 %0, %10 offset:36\n\t"
        "ds_add_f32 %0, %11 offset:40\n\t"
        "ds_add_f32 %0, %12 offset:44\n\t"
        "ds_add_f32 %0, %13 offset:48\n\t"
        "ds_add_f32 %0, %14 offset:52\n\t"
        "ds_add_f32 %0, %15 offset:56\n\t"
        "ds_add_f32 %0, %16 offset:60"
        :
        : "v"(ba), "v"(u[0]), "v"(u[1]), "v"(u[2]), "v"(u[3]), "v"(u[4]), "v"(u[5]),
          "v"(u[6]), "v"(u[7]), "v"(u[8]), "v"(u[9]), "v"(u[10]), "v"(u[11]),
          "v"(u[12]), "v"(u[13]), "v"(u[14]), "v"(u[15])
        : "memory");
}

// tanh(n)/n, branch-free, n >= 0. exp overflow -> rcp(inf)=0 -> tanh=1. OK.
__device__ __forceinline__ float squash_scale(float nsq) {
    float n = __builtin_amdgcn_sqrtf(nsq);
    float e = __expf(2.0f * n);
    float th = 1.0f - 2.0f * __builtin_amdgcn_rcpf(e + 1.0f);
    return th * __builtin_amdgcn_rcpf(n);
}

// ---------------------------------------------------------------------------
// Main kernel. wave wv <-> jj = wv; lane = b; loop over m in pairs.
// NOTE: __launch_bounds__(256) ONLY — requesting min-4-waves/SIMD in round 2
// capped VGPR at 64 and spilled ~80 floats/thread to scratch (184 MB writes).
// ---------------------------------------------------------------------------
__global__ __launch_bounds__(256) void caps_main(
    const float* __restrict__ xin,   // [B][N][8]
    const float* __restrict__ Wg,    // [N][8][160]
    const float* __restrict__ dcg,   // [10][16]
    float* __restrict__ P,           // [NBLK][PSTRIDE] or nullptr
    float* __restrict__ ACC)         // [ACC_FLOATS] (atomic fallback)
{
    __shared__ __align__(16) float W_lds[JC * 1280];   // 20 KB
    __shared__ __align__(16) float x_t[JC * 8 * 64];   // [jj][i][b]  8 KB
    __shared__ __align__(16) float dc_lds[160];
    __shared__ float S_rep[8 * 173];                   // 8 replicas of S[10*17(+T)]
    __shared__ float ub_lds[64 * 17];

    const int tid = threadIdx.x;
    const int j0 = blockIdx.x * JC;

    // ---- stage W chunk (coalesced float4) ----
    {
        const float4* wsrc = (const float4*)(Wg + (size_t)j0 * 1280);
        float4* wdst = (float4*)W_lds;
        #pragma unroll
        for (int s = 0; s < 5; ++s) wdst[tid + 256 * s] = wsrc[tid + 256 * s];
    }
    // ---- stage x transposed: x_t[jj][i][b] ----
    #pragma unroll
    for (int s = 0; s < 2; ++s) {
        int idx = tid + 256 * s;            // 0..511
        int b = idx >> 3, p = idx & 7;
        const float* src = xin + (size_t)b * (NPOS * DIN_) + (size_t)j0 * DIN_ + p * 4;
        float4 v = *(const float4*)src;
        #pragma unroll
        for (int k = 0; k < 4; ++k) {
            int f = p * 4 + k;              // 0..31 = jj*8+i
            float fv = (k == 0) ? v.x : (k == 1) ? v.y : (k == 2) ? v.z : v.w;
            x_t[(f >> 3) * 512 + (f & 7) * 64 + b] = fv;
        }
    }
    if (tid < 40) ((float4*)dc_lds)[tid] = ((const float4*)dcg)[tid];
    for (int q = tid; q < 8 * 173; q += 256) S_rep[q] = 0.0f;
    for (int q = tid; q < 64 * 17; q += 256) ub_lds[q] = 0.0f;
    __syncthreads();

    const int lane = tid & 63;      // = b
    const int rep  = tid & 7;       // scatter replica
    const int wv   = tid >> 6;      // wave id = jj

    const uint32_t sbase = lds_off(&S_rep[rep * 173]);

    // hoist x row for (b=lane, j=j0+wv): 8 conflict-free b32 reads, once
    float xr[DIN_];
    #pragma unroll
    for (int i = 0; i < DIN_; ++i) xr[i] = x_t[wv * 512 + i * 64 + lane];

    float ub[DVEC];
    #pragma unroll
    for (int d = 0; d < DVEC; ++d) ub[d] = 0.0f;

    const float thetas[3] = {1.0f, 0.2f, 0.1f};

    for (int p = 0; p < 5; ++p) {   // m pair {2p, 2p+1}
        // ---- u0, u1 = x (1x8) @ W columns [32p..32p+16) and [+16..+32) ----
        float u0[DVEC], u1[DVEC];
        #pragma unroll
        for (int d = 0; d < DVEC; ++d) { u0[d] = 0.0f; u1[d] = 0.0f; }
        const float* wbase = &W_lds[wv * 1280 + p * 32];
        #pragma unroll
        for (int i = 0; i < DIN_; ++i) {
            const float4* wr = (const float4*)(wbase + i * 160);
            float xi = xr[i];
            #pragma unroll
            for (int d4 = 0; d4 < 4; ++d4) {
                float4 a = wr[d4];       // m0
                float4 b = wr[d4 + 4];   // m1
                u0[4 * d4 + 0] = fmaf(xi, a.x, u0[4 * d4 + 0]);
                u0[4 * d4 + 1] = fmaf(xi, a.y, u0[4 * d4 + 1]);
                u0[4 * d4 + 2] = fmaf(xi, a.z, u0[4 * d4 + 2]);
                u0[4 * d4 + 3] = fmaf(xi, a.w, u0[4 * d4 + 3]);
                u1[4 * d4 + 0] = fmaf(xi, b.x, u1[4 * d4 + 0]);
                u1[4 * d4 + 1] = fmaf(xi, b.y, u1[4 * d4 + 1]);
                u1[4 * d4 + 2] = fmaf(xi, b.z, u1[4 * d4 + 2]);
                u1[4 * d4 + 3] = fmaf(xi, b.w, u1[4 * d4 + 3]);
            }
        }

        // ---- squash both (tree-reduced norms) ----
        {
            float a0 = fmaf(u0[0], u0[0], u0[1] * u0[1]);
            float a1 = fmaf(u0[2], u0[2], u0[3] * u0[3]);
            float a2 = fmaf(u0[4], u0[4], u0[5] * u0[5]);
            float a3 = fmaf(u0[6], u0[6], u0[7] * u0[7]);
            float a4 = fmaf(u0[8], u0[8], u0[9] * u0[9]);
            float a5 = fmaf(u0[10], u0[10], u0[11] * u0[11]);
            float a6 = fmaf(u0[12], u0[12], u0[13] * u0[13]);
            float a7 = fmaf(u0[14], u0[14], u0[15] * u0[15]);
            float n0 = ((a0 + a1) + (a2 + a3)) + ((a4 + a5) + (a6 + a7));
            float sc0 = squash_scale(n0);
            float b0 = fmaf(u1[0], u1[0], u1[1] * u1[1]);
            float b1 = fmaf(u1[2], u1[2], u1[3] * u1[3]);
            float b2 = fmaf(u1[4], u1[4], u1[5] * u1[5]);
            float b3 = fmaf(u1[6], u1[6], u1[7] * u1[7]);
            float b4 = fmaf(u1[8], u1[8], u1[9] * u1[9]);
            float b5 = fmaf(u1[10], u1[10], u1[11] * u1[11]);
            float b6 = fmaf(u1[12], u1[12], u1[13] * u1[13]);
            float b7 = fmaf(u1[14], u1[14], u1[15] * u1[15]);
            float n1 = ((b0 + b1) + (b2 + b3)) + ((b4 + b5) + (b6 + b7));
            float sc1 = squash_scale(n1);
            #pragma unroll
            for (int d = 0; d < DVEC; ++d) {
                u0[d] *= sc0; u1[d] *= sc1;
                ub[d] += u0[d] + u1[d];
            }
        }

        // ---- sims vs 10 digit caps (dc read once per pair) ----
        float s0[CCAP], s1[CCAP];
        #pragma unroll
        for (int c = 0; c < CCAP; ++c) {
            const float4* dcr = (const float4*)&dc_lds[c * 16];
            float4 d0 = dcr[0], d1 = dcr[1], d2 = dcr[2], d3 = dcr[3];
            float p00 = fmaf(u0[0], d0.x, u0[1] * d0.y);
            float p01 = fmaf(u0[2], d0.z, u0[3] * d0.w);
            float p02 = fmaf(u0[4], d1.x, u0[5] * d1.y);
            float p03 = fmaf(u0[6], d1.z, u0[7] * d1.w);
            float p04 = fmaf(u0[8], d2.x, u0[9] * d2.y);
            float p05 = fmaf(u0[10], d2.z, u0[11] * d2.w);
            float p06 = fmaf(u0[12], d3.x, u0[13] * d3.y);
            float p07 = fmaf(u0[14], d3.z, u0[15] * d3.w);
            s0[c] = ((p00 + p01) + (p02 + p03)) + ((p04 + p05) + (p06 + p07));
            float p10 = fmaf(u1[0], d0.x, u1[1] * d0.y);
            float p11 = fmaf(u1[2], d0.z, u1[3] * d0.w);
            float p12 = fmaf(u1[4], d1.x, u1[5] * d1.y);
            float p13 = fmaf(u1[6], d1.z, u1[7] * d1.w);
            float p14 = fmaf(u1[8], d2.x, u1[9] * d2.y);
            float p15 = fmaf(u1[10], d2.z, u1[11] * d2.w);
            float p16 = fmaf(u1[12], d3.x, u1[13] * d3.y);
            float p17 = fmaf(u1[14], d3.z, u1[15] * d3.w);
            s1[c] = ((p10 + p11) + (p12 + p13)) + ((p14 + p15) + (p16 + p17));
        }

        // ---- exact reference winner semantics, event 0 then event 1 ----
        // mask in {1,0,-1} tracked as two bitmasks: v = once? (twice? -s : 0) : s
        #pragma unroll
        for (int ev = 0; ev < 2; ++ev) {
            const float* s = (ev == 0) ? s0 : s1;
            const float* u = (ev == 0) ? u0 : u1;
            unsigned once = 0, twice = 0;
            #pragma unroll
            for (int t = 0; t < 3; ++t) {
                float best = -1e30f;
                int win = 0;
                #pragma unroll
                for (int c = 0; c < CCAP; ++c) {
                    float sv = s[c];
                    float v = (once & (1u << c)) ? ((twice & (1u << c)) ? -sv : 0.0f) : sv;
                    if (v > best) { best = v; win = c; }
                }
                twice |= (once & (1u << win));
                once  |= (1u << win);
                lds_scatter17(sbase + (uint32_t)(win * 68), u, thetas[t]);
            }
        }
    }

    // per-lane ubar fold (native ds_add, inter-wave accumulation)
    lds_scatter16(lds_off(&ub_lds[lane * 17]), ub);
    __syncthreads();

    // ---- block epilogue: fold 8 replicas, emit 1194 partials ----
    if (P != nullptr) {
        float* prow = P + (size_t)blockIdx.x * PSTRIDE;
        for (int qq = tid; qq < ACC_FLOATS; qq += 256) {
            float v;
            if (qq < 160) {
                int c = qq >> 4, d = qq & 15;
                v = 0.0f;
                #pragma unroll
                for (int r = 0; r < 8; ++r) v += S_rep[r * 173 + c * 17 + d];
            } else if (qq < 170) {
                int c = qq - 160;
                v = 0.0f;
                #pragma unroll
                for (int r = 0; r < 8; ++r) v += S_rep[r * 173 + c * 17 + 16];
            } else {
                int x = qq - 170;
                v = ub_lds[(x >> 4) * 17 + (x & 15)];
            }
            prow[qq] = v;
        }
    } else {
        for (int qq = tid; qq < ACC_FLOATS; qq += 256) {
            float v;
            if (qq < 160) {
                int c = qq >> 4, d = qq & 15;
                v = 0.0f;
                #pragma unroll
                for (int r = 0; r < 8; ++r) v += S_rep[r * 173 + c * 17 + d];
            } else if (qq < 170) {
                int c = qq - 160;
                v = 0.0f;
                #pragma unroll
                for (int r = 0; r < 8; ++r) v += S_rep[r * 173 + c * 17 + 16];
            } else {
                int x = qq - 170;
                v = ub_lds[(x >> 4) * 17 + (x & 15)];
            }
            unsafeAtomicAdd(&ACC[qq], v);
        }
    }
}

// ---------------------------------------------------------------------------
// Reduce block partials: 98 blocks x 16 rows each, atomic fold to ACC
// ---------------------------------------------------------------------------
__global__ __launch_bounds__(256) void caps_reduce(const float* __restrict__ P,
                                                   float* __restrict__ ACC)
{
    const int t = threadIdx.x;
    float acc[5] = {0.f, 0.f, 0.f, 0.f, 0.f};
    const int r0 = blockIdx.x * 16;
    for (int r = 0; r < 16; ++r) {
        const float* row = P + (size_t)(r0 + r) * PSTRIDE;
        #pragma unroll
        for (int s = 0; s < 5; ++s) {
            int col = t + 256 * s;
            float v = (col < ACC_FLOATS) ? row[col] : 0.0f;
            acc[s] += v;
        }
    }
    #pragma unroll
    for (int s = 0; s < 5; ++s) {
        int col = t + 256 * s;
        if (col < ACC_FLOATS) unsafeAtomicAdd(&ACC[col], acc[s]);
    }
}

// ---------------------------------------------------------------------------
// Finalize: dc update + row-normalize, logits = (ubar/Nm)·dc_new, softmax
// ---------------------------------------------------------------------------
__global__ __launch_bounds__(256) void caps_final(const float* __restrict__ ACC,
                                                  const float* __restrict__ dcg,
                                                  float* __restrict__ outp)
{
    __shared__ float dcn[160];
    __shared__ float rnm[10];
    __shared__ float lg[640];
    const int t = threadIdx.x;

    if (t < 160) {
        int c = t >> 4;
        float d0 = dcg[t];
        float upd = (ACC[t] - ACC[160 + c] * d0) * (float)(1.0 / 4014080.0); // /(B*N*m)
        dcn[t] = d0 + upd;
    }
    __syncthreads();
    if (t < 10) {
        float s = 0.0f;
        #pragma unroll
        for (int d = 0; d < 16; ++d) s += dcn[t * 16 + d] * dcn[t * 16 + d];
        rnm[t] = 1.0f / sqrtf(s);
    }
    __syncthreads();
    if (t < 160) dcn[t] *= rnm[t >> 4];
    __syncthreads();

    for (int q = t; q < 640; q += 256) {
        int b = q / 10, c = q - 10 * b;
        const float* ubp = &ACC[170 + b * 16];
        float s = 0.0f;
        #pragma unroll
        for (int d = 0; d < 16; ++d) s += ubp[d] * dcn[c * 16 + d];
        lg[q] = s * (float)(1.0 / 62720.0);   // mean over Nm
    }
    __syncthreads();
    if (t < 64) {
        float mx = lg[t * 10];
        #pragma unroll
        for (int c = 1; c < 10; ++c) mx = fmaxf(mx, lg[t * 10 + c]);
        float e[10];
        float ssum = 0.0f;
        #pragma unroll
        for (int c = 0; c < 10; ++c) { e[c] = expf(lg[t * 10 + c] - mx); ssum += e[c]; }
        float inv = 1.0f / ssum;
        #pragma unroll
        for (int c = 0; c < 10; ++c) outp[t * 10 + c] = e[c] * inv;
    }
}

extern "C" void kernel_launch(void* const* d_in, const int* in_sizes, int n_in,
                              void* d_out, int out_size, void* d_ws, size_t ws_size,
                              hipStream_t stream)
{
    const float* xin = (const float*)d_in[0];
    const float* Wg  = (const float*)d_in[1];
    const float* dcg = (const float*)d_in[2];
    float* outp = (float*)d_out;
    float* ws = (float*)d_ws;
    float* ACC = ws;

    const size_t need = (size_t)(P_OFF + (size_t)NBLK * PSTRIDE) * sizeof(float);
    float* P = (ws_size >= need) ? (ws + P_OFF) : nullptr;

    hipMemsetAsync(ACC, 0, ACC_FLOATS * sizeof(float), stream);
    caps_main<<<dim3(NBLK), dim3(256), 0, stream>>>(xin, Wg, dcg, P, ACC);
    if (P) caps_reduce<<<dim3(98), dim3(256), 0, stream>>>(P, ACC);
    caps_final<<<dim3(1), dim3(256), 0, stream>>>(ACC, dcg, outp);
}

// Round 4
// 615.275 us; speedup vs baseline: 2.0795x; 2.0795x over previous
//
#include <hip/hip_runtime.h>
#include <math.h>

// Problem constants: B=64, N=14*14*32=6272, DIN=8, D=16, M=10, C=10
#define NPOS 6272
#define DIN_ 8
#define DVEC 16
#define CCAP 10
#define JC 4                    // capsule positions per block
#define NBLK (NPOS / JC)        // 1568 blocks
#define PSTRIDE 1200            // padded partial row (floats)
#define ACC_FLOATS 1194         // S[160] + T[10] + ubar[64*16]
#define P_OFF 1280              // float offset of partials in ws
#define NREP 32                 // lane-private scatter replicas
#define RSTRIDE 171             // words; 171 mod 32 = 11 (odd) -> replicas spread banks

__device__ __forceinline__ uint32_t lds_off(const void* p) {
    return (uint32_t)(uintptr_t)p;   // low 32 bits of generic LDS ptr = LDS byte offset
}

// 16 values into LDS at byte-offset ba. Native ds_add_f32: fire-and-forget.
__device__ __forceinline__ void lds_scatter16(uint32_t ba, const float* u) {
    asm volatile(
        "ds_add_f32 %0, %1\n\t"
        "ds_add_f32 %0, %2 offset:4\n\t"
        "ds_add_f32 %0, %3 offset:8\n\t"
        "ds_add_f32 %0, %4 offset:12\n\t"
        "ds_add_f32 %0, %5 offset:16\n\t"
        "ds_add_f32 %0, %6 offset:20\n\t"
        "ds_add_f32 %0, %7 offset:24\n\t"
        "ds_add_f32 %0, %8 offset:28\n\t"
        "ds_add_f32 %0, %9 offset:32\n\t"
        "ds_add_f32 %0, %10 offset:36\n\t"
        "ds_add_f32 %0, %11 offset:40\n\t"
        "ds_add_f32 %0, %12 offset:44\n\t"
        "ds_add_f32 %0, %13 offset:48\n\t"
        "ds_add_f32 %0, %14 offset:52\n\t"
        "ds_add_f32 %0, %15 offset:56\n\t"
        "ds_add_f32 %0, %16 offset:60"
        :
        : "v"(ba), "v"(u[0]), "v"(u[1]), "v"(u[2]), "v"(u[3]), "v"(u[4]), "v"(u[5]),
          "v"(u[6]), "v"(u[7]), "v"(u[8]), "v"(u[9]), "v"(u[10]), "v"(u[11]),
          "v"(u[12]), "v"(u[13]), "v"(u[14]), "v"(u[15])
        : "memory");
}

__device__ __forceinline__ void lds_scatter10(uint32_t ba, const float* t) {
    asm volatile(
        "ds_add_f32 %0, %1\n\t"
        "ds_add_f32 %0, %2 offset:4\n\t"
        "ds_add_f32 %0, %3 offset:8\n\t"
        "ds_add_f32 %0, %4 offset:12\n\t"
        "ds_add_f32 %0, %5 offset:16\n\t"
        "ds_add_f32 %0, %6 offset:20\n\t"
        "ds_add_f32 %0, %7 offset:24\n\t"
        "ds_add_f32 %0, %8 offset:28\n\t"
        "ds_add_f32 %0, %9 offset:32\n\t"
        "ds_add_f32 %0, %10 offset:36"
        :
        : "v"(ba), "v"(t[0]), "v"(t[1]), "v"(t[2]), "v"(t[3]), "v"(t[4]),
          "v"(t[5]), "v"(t[6]), "v"(t[7]), "v"(t[8]), "v"(t[9])
        : "memory");
}

// tanh(n)/n, branch-free, n >= 0. exp overflow -> rcp(inf)=0 -> tanh=1. OK.
__device__ __forceinline__ float squash_scale(float nsq) {
    float n = __builtin_amdgcn_sqrtf(nsq);
    float e = __expf(2.0f * n);
    float th = 1.0f - 2.0f * __builtin_amdgcn_rcpf(e + 1.0f);
    return th * __builtin_amdgcn_rcpf(n);
}

// ---------------------------------------------------------------------------
// Main kernel. wave wv <-> jj = wv; lane = b; single-m event loop.
// Winner accumulation is register-resident (S[10][16], T[10]) via per-class
// weights w_c = sum_t theta_t*[win_t==c] -- NO LDS atomics in the main loop.
// (Rounds 1-3 all hit the same ~1270us wall: same-address ds_add serialization,
//  ~30 cyc/colliding lane. 8 lanes/address x 510 ops/thread = the whole wall.)
// ---------------------------------------------------------------------------
__global__ __launch_bounds__(256) void caps_main(
    const float* __restrict__ xin,   // [B][N][8]
    const float* __restrict__ Wg,    // [N][8][160]
    const float* __restrict__ dcg,   // [10][16]
    float* __restrict__ P,           // [NBLK][PSTRIDE] or nullptr
    float* __restrict__ ACC)         // [ACC_FLOATS] (atomic fallback)
{
    __shared__ __align__(16) float W_lds[JC * 1280];   // 20480 B
    __shared__ __align__(16) float x_t[JC * 8 * 64];   // [jj][i][b]  8192 B
    __shared__ __align__(16) float dc_lds[160];        // 640 B
    __shared__ float S_rep[NREP * RSTRIDE];            // 21888 B (32 replicas x 170+pad)
    __shared__ float ub_lds[64 * 17];                  // 4352 B

    const int tid = threadIdx.x;
    const int j0 = blockIdx.x * JC;

    // ---- stage W chunk (coalesced float4) ----
    {
        const float4* wsrc = (const float4*)(Wg + (size_t)j0 * 1280);
        float4* wdst = (float4*)W_lds;
        #pragma unroll
        for (int s = 0; s < 5; ++s) wdst[tid + 256 * s] = wsrc[tid + 256 * s];
    }
    // ---- stage x transposed: x_t[jj][i][b] ----
    #pragma unroll
    for (int s = 0; s < 2; ++s) {
        int idx = tid + 256 * s;            // 0..511
        int b = idx >> 3, p = idx & 7;
        const float* src = xin + (size_t)b * (NPOS * DIN_) + (size_t)j0 * DIN_ + p * 4;
        float4 v = *(const float4*)src;
        #pragma unroll
        for (int k = 0; k < 4; ++k) {
            int f = p * 4 + k;              // 0..31 = jj*8+i
            float fv = (k == 0) ? v.x : (k == 1) ? v.y : (k == 2) ? v.z : v.w;
            x_t[(f >> 3) * 512 + (f & 7) * 64 + b] = fv;
        }
    }
    if (tid < 40) ((float4*)dc_lds)[tid] = ((const float4*)dcg)[tid];
    for (int q = tid; q < NREP * RSTRIDE; q += 256) S_rep[q] = 0.0f;
    for (int q = tid; q < 64 * 17; q += 256) ub_lds[q] = 0.0f;
    __syncthreads();

    const int lane = tid & 63;      // = b
    const int rep  = tid & (NREP - 1);
    const int wv   = tid >> 6;      // wave id = jj

    // hoist x row for (b=lane, j=j0+wv): 8 conflict-free b32 reads, once
    float xr[DIN_];
    #pragma unroll
    for (int i = 0; i < DIN_; ++i) xr[i] = x_t[wv * 512 + i * 64 + lane];

    // register-resident accumulators (all statically indexed -> stay in VGPRs)
    float S[CCAP][DVEC];
    float T[CCAP];
    float ub[DVEC];
    #pragma unroll
    for (int c = 0; c < CCAP; ++c) {
        T[c] = 0.0f;
        #pragma unroll
        for (int d = 0; d < DVEC; ++d) S[c][d] = 0.0f;
    }
    #pragma unroll
    for (int d = 0; d < DVEC; ++d) ub[d] = 0.0f;

    for (int m = 0; m < 10; ++m) {
        // ---- u[16] = x (1x8) @ W_j[:, m*16 .. m*16+16)  (broadcast b128 reads) ----
        float u[DVEC];
        #pragma unroll
        for (int d = 0; d < DVEC; ++d) u[d] = 0.0f;
        const float* wbase = &W_lds[wv * 1280 + m * 16];
        #pragma unroll
        for (int i = 0; i < DIN_; ++i) {
            const float4* wr = (const float4*)(wbase + i * 160);
            float xi = xr[i];
            #pragma unroll
            for (int d4 = 0; d4 < 4; ++d4) {
                float4 a = wr[d4];
                u[4 * d4 + 0] = fmaf(xi, a.x, u[4 * d4 + 0]);
                u[4 * d4 + 1] = fmaf(xi, a.y, u[4 * d4 + 1]);
                u[4 * d4 + 2] = fmaf(xi, a.z, u[4 * d4 + 2]);
                u[4 * d4 + 3] = fmaf(xi, a.w, u[4 * d4 + 3]);
            }
        }

        // ---- squash (tree-reduced norm) ----
        {
            float a0 = fmaf(u[0], u[0], u[1] * u[1]);
            float a1 = fmaf(u[2], u[2], u[3] * u[3]);
            float a2 = fmaf(u[4], u[4], u[5] * u[5]);
            float a3 = fmaf(u[6], u[6], u[7] * u[7]);
            float a4 = fmaf(u[8], u[8], u[9] * u[9]);
            float a5 = fmaf(u[10], u[10], u[11] * u[11]);
            float a6 = fmaf(u[12], u[12], u[13] * u[13]);
            float a7 = fmaf(u[14], u[14], u[15] * u[15]);
            float nsq = ((a0 + a1) + (a2 + a3)) + ((a4 + a5) + (a6 + a7));
            float sc = squash_scale(nsq);
            #pragma unroll
            for (int d = 0; d < DVEC; ++d) { u[d] *= sc; ub[d] += u[d]; }
        }

        // ---- sims vs 10 digit caps (broadcast b128 dc reads) ----
        float s[CCAP];
        #pragma unroll
        for (int c = 0; c < CCAP; ++c) {
            const float4* dcr = (const float4*)&dc_lds[c * 16];
            float4 d0 = dcr[0], d1 = dcr[1], d2 = dcr[2], d3 = dcr[3];
            float p0 = fmaf(u[0], d0.x, u[1] * d0.y);
            float p1 = fmaf(u[2], d0.z, u[3] * d0.w);
            float p2 = fmaf(u[4], d1.x, u[5] * d1.y);
            float p3 = fmaf(u[6], d1.z, u[7] * d1.w);
            float p4 = fmaf(u[8], d2.x, u[9] * d2.y);
            float p5 = fmaf(u[10], d2.z, u[11] * d2.w);
            float p6 = fmaf(u[12], d3.x, u[13] * d3.y);
            float p7 = fmaf(u[14], d3.z, u[15] * d3.w);
            s[c] = ((p0 + p1) + (p2 + p3)) + ((p4 + p5) + (p6 + p7));
        }

        // ---- exact reference winner semantics (3 rounds, mask in {1,0,-1}) ----
        int win0, win1, win2;
        {
            unsigned once = 0, twice = 0;
            #pragma unroll
            for (int t = 0; t < 3; ++t) {
                float best = -1e30f;
                int win = 0;
                #pragma unroll
                for (int c = 0; c < CCAP; ++c) {
                    float sv = s[c];
                    float v = (once & (1u << c)) ? ((twice & (1u << c)) ? -sv : 0.0f) : sv;
                    if (v > best) { best = v; win = c; }
                }
                twice |= (once & (1u << win));
                once  |= (1u << win);
                if (t == 0) win0 = win; else if (t == 1) win1 = win; else win2 = win;
            }
        }

        // ---- dense weighted accumulate: S[c] += w_c * u, T[c] += w_c ----
        #pragma unroll
        for (int c = 0; c < CCAP; ++c) {
            float w = (win0 == c ? 1.0f : 0.0f);
            w += (win1 == c) ? 0.2f : 0.0f;
            w += (win2 == c) ? 0.1f : 0.0f;
            T[c] += w;
            #pragma unroll
            for (int d = 0; d < DVEC; ++d) S[c][d] = fmaf(w, u[d], S[c][d]);
        }
    }

    // ---- one scatter at the end: 32 lane-private replicas (<=2-way same-addr) ----
    {
        const uint32_t sb = lds_off(&S_rep[rep * RSTRIDE]);
        #pragma unroll
        for (int c = 0; c < CCAP; ++c) lds_scatter16(sb + (uint32_t)(c * 64), S[c]);
        lds_scatter10(sb + 640u, T);
        lds_scatter16(lds_off(&ub_lds[lane * 17]), ub);
    }
    __syncthreads();

    // ---- block epilogue: fold 32 replicas, emit 1194 partials ----
    if (P != nullptr) {
        float* prow = P + (size_t)blockIdx.x * PSTRIDE;
        for (int qq = tid; qq < ACC_FLOATS; qq += 256) {
            float v;
            if (qq < 170) {
                v = 0.0f;
                #pragma unroll
                for (int r = 0; r < NREP; ++r) v += S_rep[r * RSTRIDE + qq];
            } else {
                int x = qq - 170;
                v = ub_lds[(x >> 4) * 17 + (x & 15)];
            }
            prow[qq] = v;
        }
    } else {
        for (int qq = tid; qq < ACC_FLOATS; qq += 256) {
            float v;
            if (qq < 170) {
                v = 0.0f;
                #pragma unroll
                for (int r = 0; r < NREP; ++r) v += S_rep[r * RSTRIDE + qq];
            } else {
                int x = qq - 170;
                v = ub_lds[(x >> 4) * 17 + (x & 15)];
            }
            unsafeAtomicAdd(&ACC[qq], v);
        }
    }
}

// ---------------------------------------------------------------------------
// Reduce block partials: 98 blocks x 16 rows each, atomic fold to ACC
// ---------------------------------------------------------------------------
__global__ __launch_bounds__(256) void caps_reduce(const float* __restrict__ P,
                                                   float* __restrict__ ACC)
{
    const int t = threadIdx.x;
    float acc[5] = {0.f, 0.f, 0.f, 0.f, 0.f};
    const int r0 = blockIdx.x * 16;
    for (int r = 0; r < 16; ++r) {
        const float* row = P + (size_t)(r0 + r) * PSTRIDE;
        #pragma unroll
        for (int s = 0; s < 5; ++s) {
            int col = t + 256 * s;
            float v = (col < ACC_FLOATS) ? row[col] : 0.0f;
            acc[s] += v;
        }
    }
    #pragma unroll
    for (int s = 0; s < 5; ++s) {
        int col = t + 256 * s;
        if (col < ACC_FLOATS) unsafeAtomicAdd(&ACC[col], acc[s]);
    }
}

// ---------------------------------------------------------------------------
// Finalize: dc update + row-normalize, logits = (ubar/Nm)·dc_new, softmax
// ---------------------------------------------------------------------------
__global__ __launch_bounds__(256) void caps_final(const float* __restrict__ ACC,
                                                  const float* __restrict__ dcg,
                                                  float* __restrict__ outp)
{
    __shared__ float dcn[160];
    __shared__ float rnm[10];
    __shared__ float lg[640];
    const int t = threadIdx.x;

    if (t < 160) {
        int c = t >> 4;
        float d0 = dcg[t];
        float upd = (ACC[t] - ACC[160 + c] * d0) * (float)(1.0 / 4014080.0); // /(B*N*m)
        dcn[t] = d0 + upd;
    }
    __syncthreads();
    if (t < 10) {
        float s = 0.0f;
        #pragma unroll
        for (int d = 0; d < 16; ++d) s += dcn[t * 16 + d] * dcn[t * 16 + d];
        rnm[t] = 1.0f / sqrtf(s);
    }
    __syncthreads();
    if (t < 160) dcn[t] *= rnm[t >> 4];
    __syncthreads();

    for (int q = t; q < 640; q += 256) {
        int b = q / 10, c = q - 10 * b;
        const float* ubp = &ACC[170 + b * 16];
        float s = 0.0f;
        #pragma unroll
        for (int d = 0; d < 16; ++d) s += ubp[d] * dcn[c * 16 + d];
        lg[q] = s * (float)(1.0 / 62720.0);   // mean over Nm
    }
    __syncthreads();
    if (t < 64) {
        float mx = lg[t * 10];
        #pragma unroll
        for (int c = 1; c < 10; ++c) mx = fmaxf(mx, lg[t * 10 + c]);
        float e[10];
        float ssum = 0.0f;
        #pragma unroll
        for (int c = 0; c < 10; ++c) { e[c] = expf(lg[t * 10 + c] - mx); ssum += e[c]; }
        float inv = 1.0f / ssum;
        #pragma unroll
        for (int c = 0; c < 10; ++c) outp[t * 10 + c] = e[c] * inv;
    }
}

extern "C" void kernel_launch(void* const* d_in, const int* in_sizes, int n_in,
                              void* d_out, int out_size, void* d_ws, size_t ws_size,
                              hipStream_t stream)
{
    const float* xin = (const float*)d_in[0];
    const float* Wg  = (const float*)d_in[1];
    const float* dcg = (const float*)d_in[2];
    float* outp = (float*)d_out;
    float* ws = (float*)d_ws;
    float* ACC = ws;

    const size_t need = (size_t)(P_OFF + (size_t)NBLK * PSTRIDE) * sizeof(float);
    float* P = (ws_size >= need) ? (ws + P_OFF) : nullptr;

    hipMemsetAsync(ACC, 0, ACC_FLOATS * sizeof(float), stream);
    caps_main<<<dim3(NBLK), dim3(256), 0, stream>>>(xin, Wg, dcg, P, ACC);
    if (P) caps_reduce<<<dim3(98), dim3(256), 0, stream>>>(P, ACC);
    caps_final<<<dim3(1), dim3(256), 0, stream>>>(ACC, dcg, outp);
}